// Round 20
// baseline (2074.670 us; speedup 1.0000x reference)
//
#include <hip/hip_runtime.h>
#include <cmath>

#define WIDTH 384
#define HW 147456        // 384*384
#define CHW 4718592      // 32*384*384
#define NCH 32
#define NV 2048
#define NROWS 147456     // zf rows per scale

typedef short vshort8 __attribute__((ext_vector_type(8)));
typedef float vfloat4 __attribute__((ext_vector_type(4)));

// bf16 split helper: returns RNE bf16 bits of x, sets back = that value as f32
__device__ inline unsigned short bf_split(float x, float& back) {
  unsigned int b; __builtin_memcpy(&b, &x, 4);
  unsigned int r = (b + 0x7FFFu + ((b >> 16) & 1u)) >> 16;
  unsigned int bb = r << 16; float f; __builtin_memcpy(&f, &bb, 4);
  back = f; return (unsigned short)r;
}

// ---------------------------------------------------------------------------
// numpy pairwise_sum replica, f32, contraction-proof.
// ---------------------------------------------------------------------------
template <int SQ>
__device__ float np_pw(const float* a, int n, float mu) {
  if (n < 8) {
    float res = 0.0f;
    for (int i = 0; i < n; i++) {
      float v = a[i];
      if (SQ) { float d = __fsub_rn(v, mu); v = __fmul_rn(d, d); }
      res = __fadd_rn(res, v);
    }
    return res;
  }
  if (n <= 128) {
    float r[8];
#pragma unroll
    for (int j = 0; j < 8; j++) {
      float v = a[j];
      if (SQ) { float d = __fsub_rn(v, mu); v = __fmul_rn(d, d); }
      r[j] = v;
    }
    int i;
    for (i = 8; i + 8 <= n; i += 8) {
#pragma unroll
      for (int j = 0; j < 8; j++) {
        float v = a[i + j];
        if (SQ) { float d = __fsub_rn(v, mu); v = __fmul_rn(d, d); }
        r[j] = __fadd_rn(r[j], v);
      }
    }
    float res = __fadd_rn(__fadd_rn(__fadd_rn(r[0], r[1]), __fadd_rn(r[2], r[3])),
                          __fadd_rn(__fadd_rn(r[4], r[5]), __fadd_rn(r[6], r[7])));
    for (; i < n; i++) {
      float v = a[i];
      if (SQ) { float d = __fsub_rn(v, mu); v = __fmul_rn(d, d); }
      res = __fadd_rn(res, v);
    }
    return res;
  }
  int n2 = n / 2; n2 -= n2 % 8;
  return __fadd_rn(np_pw<SQ>(a, n2, mu), np_pw<SQ>(a + n2, n - n2, mu));
}

// ---------------------------------------------------------------------------
// prep: WT transpose; EE exact numpy-pairwise |e|^2; EH/EL bf16 split of emb.
// ---------------------------------------------------------------------------
__global__ __launch_bounds__(256) void prep_kernel(
    const float* __restrict__ pw1, const float* __restrict__ pw2,
    const float* __restrict__ rw1, const float* __restrict__ rw2,
    const float* __restrict__ emb, float* __restrict__ wt, float* __restrict__ ee,
    unsigned short* __restrict__ eh, unsigned short* __restrict__ el) {
  int t = blockIdx.x * 256 + threadIdx.x;
  if (t < 147456) {
    int layer = t / 9216, r = t % 9216;
    int k = r / 32, co = r % 32;
    int set = layer >> 2, s = layer & 3;
    const float* src = set == 0 ? pw1 : set == 1 ? pw2 : set == 2 ? rw1 : rw2;
    wt[t] = src[s * 9216 + co * 288 + k];
  } else if (t < 147456 + NV) {
    int v = t - 147456;
    const float* e = emb + v * 32;
    float r[8];
#pragma unroll
    for (int j = 0; j < 8; j++) r[j] = __fmul_rn(e[j], e[j]);
#pragma unroll
    for (int i = 8; i < 32; i += 8)
#pragma unroll
      for (int j = 0; j < 8; j++) r[j] = __fadd_rn(r[j], __fmul_rn(e[i + j], e[i + j]));
    ee[v] = __fadd_rn(__fadd_rn(__fadd_rn(r[0], r[1]), __fadd_rn(r[2], r[3])),
                      __fadd_rn(__fadd_rn(r[4], r[5]), __fadd_rn(r[6], r[7])));
  } else if (t < 147456 + NV + 65536) {
    int idx = t - 147456 - NV;
    float x = emb[idx], hb;
    eh[idx] = bf_split(x, hb);
    float lb;
    el[idx] = bf_split(__fsub_rn(x, hb), lb);
  }
}

// ---------------------------------------------------------------------------
// conv3x3: one thread = one pixel, ALL 32 co. 768 x 192 = 3 blocks/CU.
// Tap double-buffer; s_load weights. Chains (ci,dy,dx) ascending — bit-exact.
// MODE 0: patch-major in -> patch-major out
// MODE 1: residual in (x - acc, image layout) -> patch-major out
// MODE 2: patch-major in; fold: acc_img += zq*0.5 + (conv+b)*0.5
// MODE 3: scale-0 residual (x only, no acc read) -> patch-major out
// MODE 4: scale-0 fold: acc_img = zq*0.5 + (conv+b)*0.5 (no acc read)
// ---------------------------------------------------------------------------
template <int MODE>
__global__ __launch_bounds__(192, 3) void conv32_kernel(
    const float* __restrict__ in, const float* __restrict__ x,
    const float* __restrict__ accin, float* __restrict__ outb,
    const float* __restrict__ zqb, float* __restrict__ acc,
    const float* __restrict__ wt, const float* __restrict__ bias, int p, int nw) {
  int t = blockIdx.x * 192 + threadIdx.x;
  int pp = p * p;
  int px = t % p; int t1 = t / p;
  int py = t1 % p;
  int n  = t1 / p;
  int i = n / nw, j = n % nw;

  const bool IMGIN = (MODE == 1 || MODE == 3);
  int off[9]; bool msk[9];
#pragma unroll
  for (int dy = 0; dy < 3; dy++) {
    int ly = py + dy - 1;
    bool vy = (unsigned)ly < (unsigned)p;
    int cy = vy ? ly : 0;
#pragma unroll
    for (int dx = 0; dx < 3; dx++) {
      int lx = px + dx - 1;
      bool vx = (unsigned)lx < (unsigned)p;
      int cx = vx ? lx : 0;
      msk[dy * 3 + dx] = vy && vx;
      if (IMGIN) off[dy * 3 + dx] = (i * p + cy) * WIDTH + (j * p + cx);
      else       off[dy * 3 + dx] = cy * p + cx;
    }
  }

  const float* pin = IMGIN ? nullptr : in + (size_t)n * NCH * pp;

  float a[NCH];
#pragma unroll
  for (int co = 0; co < NCH; co++) a[co] = 0.0f;

  float tv[9], tn[9];
#pragma unroll
  for (int k = 0; k < 9; k++) {
    float v;
    if (MODE == 1)      v = __fsub_rn(x[(size_t)off[k]], accin[(size_t)off[k]]);
    else if (MODE == 3) v = x[(size_t)off[k]];
    else                v = pin[off[k]];
    tv[k] = msk[k] ? v : 0.0f;
  }

  for (int ci = 0; ci < NCH; ci++) {
    if (ci + 1 < NCH) {
#pragma unroll
      for (int k = 0; k < 9; k++) {
        float v;
        if (MODE == 1) {
          size_t ad = (size_t)(ci + 1) * HW + off[k];
          v = __fsub_rn(x[ad], accin[ad]);
        } else if (MODE == 3) {
          v = x[(size_t)(ci + 1) * HW + off[k]];
        } else {
          v = pin[(size_t)(ci + 1) * pp + off[k]];
        }
        tn[k] = msk[k] ? v : 0.0f;
      }
    }
    const float* wp = wt + ci * 288;        // [k][co], uniform -> s_load
#pragma unroll
    for (int k = 0; k < 9; k++) {
#pragma unroll
      for (int co = 0; co < NCH; co++)
        a[co] = fmaf(tv[k], wp[k * 32 + co], a[co]);
    }
#pragma unroll
    for (int k = 0; k < 9; k++) tv[k] = tn[k];
  }

#pragma unroll
  for (int co = 0; co < NCH; co++) {
    float r = __fadd_rn(a[co], bias[co]);
    if (MODE == 2 || MODE == 4) {
      size_t img = (size_t)co * HW + (size_t)(i * p + py) * WIDTH + (j * p + px);
      size_t pt  = (size_t)n * NCH * pp + (size_t)co * pp + (size_t)py * p + px;
      float dec = __fadd_rn(__fmul_rn(zqb[pt], 0.5f), __fmul_rn(r, 0.5f));
      if (MODE == 2) acc[img] = __fadd_rn(acc[img], dec);
      else           acc[img] = __fadd_rn(0.0f, dec);   // 0+dec, same as ref
    } else {
      outb[(size_t)n * NCH * pp + (size_t)co * pp + (size_t)py * p + px] = r;
    }
  }
}

// ---------------------------------------------------------------------------
// GroupNorm stats v2: C lanes per group, shfl_xor butterfly (bit-exact).
// ---------------------------------------------------------------------------
__global__ __launch_bounds__(64) void gn_stats_kernel(
    const float* __restrict__ buf, float2* __restrict__ stats,
    int p, int C, int chunk) {
  int tid = threadIdx.x;
  int gpw = 64 / C;
  int gi = tid / C, cl = tid % C;
  int grp = blockIdx.x * gpw + gi;
  int pp = p * p, ne = 4 * pp;
  const float* base = buf + ((size_t)(grp >> 3) * NCH + (size_t)(grp & 7) * 4) * pp
                      + (size_t)cl * chunk;

  float s = np_pw<0>(base, chunk, 0.0f);
  for (int m = 1; m < C; m <<= 1) s = __fadd_rn(s, __shfl_xor(s, m, 64));
  float mu = __fdiv_rn(s, (float)ne);

  float s2 = np_pw<1>(base, chunk, mu);
  for (int m = 1; m < C; m <<= 1) s2 = __fadd_rn(s2, __shfl_xor(s2, m, 64));

  if (cl == 0) {
    float var = __fdiv_rn(s2, (float)ne);
    float rs = __fdiv_rn(1.0f, __fsqrt_rn(__fadd_rn(var, 1e-5f)));
    stats[grp] = make_float2(mu, rs);
  }
}

// ---------------------------------------------------------------------------
// GN affine + exact GELU (erf = f64 erf rounded to f32).
// ---------------------------------------------------------------------------
__global__ __launch_bounds__(256) void gn_gelu_kernel(
    float* __restrict__ buf, const float2* __restrict__ stats,
    const float* __restrict__ gamma, const float* __restrict__ beta, int p) {
  int t = blockIdx.x * 256 + threadIdx.x;
  int pp = p * p;
  int t2 = t / pp;
  int c = t2 % NCH;
  int n = t2 / NCH;
  float2 st = stats[n * 8 + (c >> 2)];
  float v = __fadd_rn(__fmul_rn(__fmul_rn(__fsub_rn(buf[t], st.x), st.y), gamma[c]), beta[c]);
  float tt = __fdiv_rn(v, 1.41421356237309504880f);
  float e = (float)erf((double)tt);
  buf[t] = __fmul_rn(__fmul_rn(0.5f, v), __fadd_rn(1.0f, e));
}

// ---------------------------------------------------------------------------
// MFMA filter pass with fused zsplit (round-18/19 known-good).
// ---------------------------------------------------------------------------
__global__ __launch_bounds__(576, 5) void gemm_min_kernel(
    const float* __restrict__ z,
    const unsigned short* __restrict__ EH, const unsigned short* __restrict__ EL,
    const float* __restrict__ EE,
    float* __restrict__ BD, float* __restrict__ B2, int* __restrict__ I1) {
  __shared__ float ee_l[2048];
  int tid = threadIdx.x;
  for (int i = tid; i < 2048; i += 576) ee_l[i] = EE[i];
  __syncthreads();

  int wid = tid / 64, lane = tid & 63;
  int t0 = blockIdx.x * 18 + wid * 2;        // two consecutive row-tiles
  int lr = lane & 15, lg = lane >> 4;

  float za0[8], za1[8];
  {
    const float4* zp0 = (const float4*)(z + (size_t)(t0 * 16 + lr) * 32 + 8 * lg);
    const float4* zp1 = (const float4*)(z + (size_t)((t0 + 1) * 16 + lr) * 32 + 8 * lg);
    float4 c0 = zp0[0], c1 = zp0[1], d0 = zp1[0], d1 = zp1[1];
    za0[0]=c0.x; za0[1]=c0.y; za0[2]=c0.z; za0[3]=c0.w;
    za0[4]=c1.x; za0[5]=c1.y; za0[6]=c1.z; za0[7]=c1.w;
    za1[0]=d0.x; za1[1]=d0.y; za1[2]=d0.z; za1[3]=d0.w;
    za1[4]=d1.x; za1[5]=d1.y; za1[6]=d1.z; za1[7]=d1.w;
  }

  // exact numpy zz via cross-lane reconstruction (chain order preserved)
  float zz0, zz1;
  {
    float r0[8], r1[8];
#pragma unroll
    for (int j = 0; j < 8; j++) {
      float p0 = __fmul_rn(za0[j], za0[j]);
      float p1 = __fmul_rn(za1[j], za1[j]);
      float a0 = __shfl(p0, lr, 64),      a1 = __shfl(p0, 16 + lr, 64);
      float a2 = __shfl(p0, 32 + lr, 64), a3 = __shfl(p0, 48 + lr, 64);
      r0[j] = __fadd_rn(__fadd_rn(__fadd_rn(a0, a1), a2), a3);
      float b0 = __shfl(p1, lr, 64),      b1 = __shfl(p1, 16 + lr, 64);
      float b2_ = __shfl(p1, 32 + lr, 64), b3 = __shfl(p1, 48 + lr, 64);
      r1[j] = __fadd_rn(__fadd_rn(__fadd_rn(b0, b1), b2_), b3);
    }
    zz0 = __fadd_rn(__fadd_rn(__fadd_rn(r0[0], r0[1]), __fadd_rn(r0[2], r0[3])),
                    __fadd_rn(__fadd_rn(r0[4], r0[5]), __fadd_rn(r0[6], r0[7])));
    zz1 = __fadd_rn(__fadd_rn(__fadd_rn(r1[0], r1[1]), __fadd_rn(r1[2], r1[3])),
                    __fadd_rn(__fadd_rn(r1[4], r1[5]), __fadd_rn(r1[6], r1[7])));
  }
  float zzv[8];
#pragma unroll
  for (int r = 0; r < 4; r++) {
    zzv[r]     = __shfl(zz0, 4 * lg + r, 64);
    zzv[4 + r] = __shfl(zz1, 4 * lg + r, 64);
  }

  vshort8 azh0, azl0, azh1, azl1;
#pragma unroll
  for (int j = 0; j < 8; j++) {
    float hb;
    azh0[j] = (short)bf_split(za0[j], hb);
    float lb;
    azl0[j] = (short)bf_split(__fsub_rn(za0[j], hb), lb);
    azh1[j] = (short)bf_split(za1[j], hb);
    azl1[j] = (short)bf_split(__fsub_rn(za1[j], hb), lb);
  }

  float b1[8], b2[8]; int i1[8];
#pragma unroll
  for (int r = 0; r < 8; r++) { b1[r] = 3.402823466e+38f; b2[r] = 3.402823466e+38f; i1[r] = 0; }

  vshort8 nbeh = *(const vshort8*)(EH + (size_t)lr * 32 + 8 * lg);
  vshort8 nbel = *(const vshort8*)(EL + (size_t)lr * 32 + 8 * lg);

  for (int ct = 0; ct < 128; ct++) {
    vshort8 beh = nbeh, bel = nbel;
    if (ct + 1 < 128) {
      nbeh = *(const vshort8*)(EH + (size_t)((ct + 1) * 16 + lr) * 32 + 8 * lg);
      nbel = *(const vshort8*)(EL + (size_t)((ct + 1) * 16 + lr) * 32 + 8 * lg);
    }
    vfloat4 acc0 = {0.0f, 0.0f, 0.0f, 0.0f};
    acc0 = __builtin_amdgcn_mfma_f32_16x16x32_bf16(azh0, beh, acc0, 0, 0, 0);
    acc0 = __builtin_amdgcn_mfma_f32_16x16x32_bf16(azh0, bel, acc0, 0, 0, 0);
    acc0 = __builtin_amdgcn_mfma_f32_16x16x32_bf16(azl0, beh, acc0, 0, 0, 0);
    vfloat4 acc1 = {0.0f, 0.0f, 0.0f, 0.0f};
    acc1 = __builtin_amdgcn_mfma_f32_16x16x32_bf16(azh1, beh, acc1, 0, 0, 0);
    acc1 = __builtin_amdgcn_mfma_f32_16x16x32_bf16(azh1, bel, acc1, 0, 0, 0);
    acc1 = __builtin_amdgcn_mfma_f32_16x16x32_bf16(azl1, beh, acc1, 0, 0, 0);
    int col = ct * 16 + lr;
    float eev = ee_l[col];
#pragma unroll
    for (int r = 0; r < 4; r++) {
      float d = (zzv[r] + eev) - 2.0f * acc0[r];
      if (d < b1[r]) { b2[r] = b1[r]; b1[r] = d; i1[r] = col; }
      else b2[r] = fminf(b2[r], d);
      float d1 = (zzv[4 + r] + eev) - 2.0f * acc1[r];
      if (d1 < b1[4 + r]) { b2[4 + r] = b1[4 + r]; b1[4 + r] = d1; i1[4 + r] = col; }
      else b2[4 + r] = fminf(b2[4 + r], d1);
    }
  }

  for (int m = 1; m < 16; m <<= 1) {
#pragma unroll
    for (int r = 0; r < 8; r++) {
      float ob1 = __shfl_xor(b1[r], m, 64);
      int   oi1 = __shfl_xor(i1[r], m, 64);
      float ob2 = __shfl_xor(b2[r], m, 64);
      bool aw = (b1[r] < ob1) || (b1[r] == ob1 && i1[r] < oi1);
      float lo = aw ? ob1 : b1[r];
      b1[r] = aw ? b1[r] : ob1;
      i1[r] = aw ? i1[r] : oi1;
      b2[r] = fminf(fminf(b2[r], ob2), lo);
    }
  }

  if (lr == 0) {
#pragma unroll
    for (int r = 0; r < 4; r++) {
      int row0 = t0 * 16 + 4 * lg + r;
      BD[row0] = b1[r]; B2[row0] = b2[r]; I1[row0] = i1[r];
      int row1 = (t0 + 1) * 16 + 4 * lg + r;
      BD[row1] = b1[4 + r]; B2[row1] = b2[4 + r]; I1[row1] = i1[4 + r];
    }
  }
}

// ---------------------------------------------------------------------------
// Fused epilogue: 4 threads/row float4 zq/idx writes + per-wave ballot
// rescore of flagged rows (r14 wave-cooperative exact scan: identical f32
// chains + lex-(d,v) butterfly = np.argmin first-occurrence) + block-level
// f64 SSE partials. No atomics, no LIST/SSEP round-trips.
// ---------------------------------------------------------------------------
__global__ __launch_bounds__(256) void epilogue_kernel(
    const float* __restrict__ z, const float* __restrict__ emb,
    const float* __restrict__ EE,
    const float* __restrict__ BD, const float* __restrict__ B2,
    const int* __restrict__ I1, float* __restrict__ zq,
    float* __restrict__ idxout, double* __restrict__ part) {
  __shared__ double red[256];
  int tid = threadIdx.x;
  int lane = tid & 63;
  int t = blockIdx.x * 256 + tid;           // grid exact: 2304*256 = 589824
  int row = t >> 2, quarter = t & 3;
  float bd = BD[row];
  int bi = I1[row];
  float margin = __fadd_rn(1.0e-6f, __fmul_rn(5.0e-7f, fabsf(bd)));
  bool flagged = (B2[row] - bd) <= margin;

  // wave-cooperative exact rescore of this wave's flagged rows
  unsigned long long mask = __ballot(flagged && quarter == 0);
  while (mask) {
    int l = __ffsll((long long)mask) - 1;
    mask &= mask - 1;
    int rrow = __shfl(row, l, 64);          // wave-uniform target row
    const float* zp = z + (size_t)rrow * 32; // uniform -> scalar loads
    float zb[32];
#pragma unroll
    for (int q = 0; q < 32; q++) zb[q] = zp[q];
    // exact numpy zz chain (redundant per lane, identical value)
    float rr[8];
#pragma unroll
    for (int j = 0; j < 8; j++) rr[j] = __fmul_rn(zb[j], zb[j]);
#pragma unroll
    for (int ii = 8; ii < 32; ii += 8)
#pragma unroll
      for (int j = 0; j < 8; j++) rr[j] = __fadd_rn(rr[j], __fmul_rn(zb[ii + j], zb[ii + j]));
    float zzb = __fadd_rn(__fadd_rn(__fadd_rn(rr[0], rr[1]), __fadd_rn(rr[2], rr[3])),
                          __fadd_rn(__fadd_rn(rr[4], rr[5]), __fadd_rn(rr[6], rr[7])));
    float bestd = 3.402823466e+38f;
    int bestv = NV;
    for (int k = 0; k < 32; k++) {
      int v = lane + 64 * k;
      const float* e0 = emb + (size_t)v * 32;
      float m = 0.0f;
#pragma unroll
      for (int q = 0; q < 32; q++) m = fmaf(zb[q], e0[q], m);
      float d = __fsub_rn(__fadd_rn(zzb, EE[v]), __fmul_rn(2.0f, m));
      if (d < bestd) { bestd = d; bestv = v; } // v ascending within lane
    }
    for (int mm = 1; mm < 64; mm <<= 1) {      // lexicographic (d, v) butterfly
      float od = __shfl_xor(bestd, mm, 64);
      int ov = __shfl_xor(bestv, mm, 64);
      if (od < bestd || (od == bestd && ov < bestv)) { bestd = od; bestv = ov; }
    }
    if (row == rrow) bi = bestv;            // all 4 owning lanes adopt
  }

  // write zq/idx + per-quarter f64 SSE with the final bi
  const float4* ep = (const float4*)(emb + (size_t)bi * 32 + quarter * 8);
  const float4* zp = (const float4*)(z + (size_t)row * 32 + quarter * 8);
  float4* qp = (float4*)(zq + (size_t)row * 32 + quarter * 8);
  float4 e0 = ep[0], e1 = ep[1];
  float4 z0 = zp[0], z1 = zp[1];
  qp[0] = e0; qp[1] = e1;
  double sse = 0.0, d;
  d = (double)e0.x - (double)z0.x; sse += d * d;
  d = (double)e0.y - (double)z0.y; sse += d * d;
  d = (double)e0.z - (double)z0.z; sse += d * d;
  d = (double)e0.w - (double)z0.w; sse += d * d;
  d = (double)e1.x - (double)z1.x; sse += d * d;
  d = (double)e1.y - (double)z1.y; sse += d * d;
  d = (double)e1.z - (double)z1.z; sse += d * d;
  d = (double)e1.w - (double)z1.w; sse += d * d;
  if (quarter == 0) idxout[row] = (float)bi;

  red[tid] = sse;
  __syncthreads();
  for (int st = 128; st > 0; st >>= 1) {
    if (tid < st) red[tid] += red[tid + st];
    __syncthreads();
  }
  if (tid == 0) part[blockIdx.x] = red[0];
}

__global__ __launch_bounds__(256) void sigmoid_kernel(
    const float* __restrict__ acc, float* __restrict__ out) {
  int t = blockIdx.x * 256 + threadIdx.x;
  out[t] = (float)(1.0 / (1.0 + exp(-(double)acc[t])));
}

// 256-thread deterministic loss reduction over 4 x 2304 partials
__global__ __launch_bounds__(256) void loss_kernel(
    const double* __restrict__ part, float* __restrict__ out) {
  __shared__ double red[256];
  int tid = threadIdx.x;
  double tot = 0.0;
  for (int s = 0; s < 4; s++) {
    double sse = 0.0;
    for (int b = tid; b < 2304; b += 256) sse += part[s * 2304 + b];
    red[tid] = sse;
    __syncthreads();
    for (int st = 128; st > 0; st >>= 1) {
      if (tid < st) red[tid] += red[tid + st];
      __syncthreads();
    }
    if (tid == 0) tot += 1.25 * red[0] / 4718592.0;
    __syncthreads();
  }
  if (tid == 0) out[0] = (float)tot;
}

// ---------------------------------------------------------------------------
extern "C" void kernel_launch(void* const* d_in, const int* in_sizes, int n_in,
                              void* d_out, int out_size, void* d_ws, size_t ws_size,
                              hipStream_t stream) {
  const float* X   = (const float*)d_in[0];
  const float* EMB = (const float*)d_in[1];
  const float* PW1 = (const float*)d_in[2];
  const float* PB1 = (const float*)d_in[3];
  const float* PG  = (const float*)d_in[4];
  const float* PBT = (const float*)d_in[5];
  const float* PW2 = (const float*)d_in[6];
  const float* PB2 = (const float*)d_in[7];
  const float* RW1 = (const float*)d_in[8];
  const float* RB1 = (const float*)d_in[9];
  const float* RG  = (const float*)d_in[10];
  const float* RBT = (const float*)d_in[11];
  const float* RW2 = (const float*)d_in[12];
  const float* RB2 = (const float*)d_in[13];
  float* out = (float*)d_out;

  // workspace layout (~60 MiB; ws >= 115 MB established safe):
  char* w = (char*)d_ws;
  float*          EE    = (float*)(w);                      // 8,192
  float*          WT    = (float*)(w + 8192UL);             // 589,824
  unsigned short* EH    = (unsigned short*)(w + 598016UL);  // 131,072
  unsigned short* EL    = (unsigned short*)(w + 729088UL);  // 131,072
  float2*         STATS = (float2*)(w + 860160UL);          // 36,864
  double*         PART  = (double*)(w + 897024UL);          // 73,728 (4 x 2304)
  float*          BD    = (float*)(w + 970752UL);           // 589,824
  float*          B2    = (float*)(w + 1560576UL);          // 589,824
  int*            I1    = (int*)(w + 2150400UL);            // 589,824
  float*          P     = (float*)(w + 2740224UL);          // 18,874,368
  float*          H     = (float*)(w + 21614592UL);         // 18,874,368
  float*          ACC   = (float*)(w + 40488960UL);         // 18,874,368

  prep_kernel<<<840, 256, 0, stream>>>(PW1, PW2, RW1, RW2, EMB, WT, EE, EH, EL);

  const int PS[4] = {16, 32, 48, 64};
  for (int s = 0; s < 4; s++) {
    int p = PS[s], nw = 384 / p, N = nw * nw;
    int C = (p == 16) ? 8 : (p == 32) ? 32 : 64;      // numpy-split-aligned chunks
    int chunk = (4 * p * p) / C;
    int gblocks = (N * 8 * C) / 64;
    const float* wt_p1 = WT + (0 * 4 + s) * 9216;
    const float* wt_p2 = WT + (1 * 4 + s) * 9216;
    const float* wt_r1 = WT + (2 * 4 + s) * 9216;
    const float* wt_r2 = WT + (3 * 4 + s) * 9216;

    // conv_block #1 (fused unfold): (x - acc) -> H, GN+GELU in H, H -> P (z)
    if (s == 0)
      conv32_kernel<3><<<768, 192, 0, stream>>>(nullptr, X, nullptr, H, nullptr, nullptr,
                                                wt_p1, PB1 + s * 32, p, nw);
    else
      conv32_kernel<1><<<768, 192, 0, stream>>>(nullptr, X, ACC, H, nullptr, nullptr,
                                                wt_p1, PB1 + s * 32, p, nw);
    gn_stats_kernel<<<gblocks, 64, 0, stream>>>(H, STATS, p, C, chunk);
    gn_gelu_kernel<<<18432, 256, 0, stream>>>(H, STATS, PG + s * 32, PBT + s * 32, p);
    conv32_kernel<0><<<768, 192, 0, stream>>>(H, nullptr, nullptr, P, nullptr, nullptr,
                                              wt_p2, PB2 + s * 32, p, nw);
    // quantize: fused zsplit+filter GEMM + fused epilogue (rescore + SSE)
    gemm_min_kernel<<<512, 576, 0, stream>>>(P, EH, EL, EE, BD, B2, I1);
    epilogue_kernel<<<2304, 256, 0, stream>>>(P, EMB, EE, BD, B2, I1, H,
                                              out + 4718592 + s * 147456, PART + s * 2304);
    // residual conv_block on zq: H -> P, GN+GELU in P, conv+fold into ACC
    conv32_kernel<0><<<768, 192, 0, stream>>>(H, nullptr, nullptr, P, nullptr, nullptr,
                                              wt_r1, RB1 + s * 32, p, nw);
    gn_stats_kernel<<<gblocks, 64, 0, stream>>>(P, STATS, p, C, chunk);
    gn_gelu_kernel<<<18432, 256, 0, stream>>>(P, STATS, RG + s * 32, RBT + s * 32, p);
    if (s == 0)
      conv32_kernel<4><<<768, 192, 0, stream>>>(P, nullptr, nullptr, nullptr, H, ACC,
                                                wt_r2, RB2 + s * 32, p, nw);
    else
      conv32_kernel<2><<<768, 192, 0, stream>>>(P, nullptr, nullptr, nullptr, H, ACC,
                                                wt_r2, RB2 + s * 32, p, nw);
  }

  sigmoid_kernel<<<18432, 256, 0, stream>>>(ACC, out);
  loss_kernel<<<1, 256, 0, stream>>>(PART, out + 5308416);
}

// Round 21
// 1988.290 us; speedup vs baseline: 1.0434x; 1.0434x over previous
//
#include <hip/hip_runtime.h>
#include <cmath>

#define WIDTH 384
#define HW 147456        // 384*384
#define CHW 4718592      // 32*384*384
#define NCH 32
#define NV 2048
#define NROWS 147456     // zf rows per scale

typedef short vshort8 __attribute__((ext_vector_type(8)));
typedef float vfloat4 __attribute__((ext_vector_type(4)));

// bf16 split helper: returns RNE bf16 bits of x, sets back = that value as f32
__device__ inline unsigned short bf_split(float x, float& back) {
  unsigned int b; __builtin_memcpy(&b, &x, 4);
  unsigned int r = (b + 0x7FFFu + ((b >> 16) & 1u)) >> 16;
  unsigned int bb = r << 16; float f; __builtin_memcpy(&f, &bb, 4);
  back = f; return (unsigned short)r;
}

// ---------------------------------------------------------------------------
// numpy pairwise_sum replica, f32, contraction-proof.
// ---------------------------------------------------------------------------
template <int SQ>
__device__ float np_pw(const float* a, int n, float mu) {
  if (n < 8) {
    float res = 0.0f;
    for (int i = 0; i < n; i++) {
      float v = a[i];
      if (SQ) { float d = __fsub_rn(v, mu); v = __fmul_rn(d, d); }
      res = __fadd_rn(res, v);
    }
    return res;
  }
  if (n <= 128) {
    float r[8];
#pragma unroll
    for (int j = 0; j < 8; j++) {
      float v = a[j];
      if (SQ) { float d = __fsub_rn(v, mu); v = __fmul_rn(d, d); }
      r[j] = v;
    }
    int i;
    for (i = 8; i + 8 <= n; i += 8) {
#pragma unroll
      for (int j = 0; j < 8; j++) {
        float v = a[i + j];
        if (SQ) { float d = __fsub_rn(v, mu); v = __fmul_rn(d, d); }
        r[j] = __fadd_rn(r[j], v);
      }
    }
    float res = __fadd_rn(__fadd_rn(__fadd_rn(r[0], r[1]), __fadd_rn(r[2], r[3])),
                          __fadd_rn(__fadd_rn(r[4], r[5]), __fadd_rn(r[6], r[7])));
    for (; i < n; i++) {
      float v = a[i];
      if (SQ) { float d = __fsub_rn(v, mu); v = __fmul_rn(d, d); }
      res = __fadd_rn(res, v);
    }
    return res;
  }
  int n2 = n / 2; n2 -= n2 % 8;
  return __fadd_rn(np_pw<SQ>(a, n2, mu), np_pw<SQ>(a + n2, n - n2, mu));
}

// ---------------------------------------------------------------------------
// prep: WT transpose; EE exact numpy-pairwise |e|^2; EH/EL bf16 split of emb.
// ---------------------------------------------------------------------------
__global__ __launch_bounds__(256) void prep_kernel(
    const float* __restrict__ pw1, const float* __restrict__ pw2,
    const float* __restrict__ rw1, const float* __restrict__ rw2,
    const float* __restrict__ emb, float* __restrict__ wt, float* __restrict__ ee,
    unsigned short* __restrict__ eh, unsigned short* __restrict__ el) {
  int t = blockIdx.x * 256 + threadIdx.x;
  if (t < 147456) {
    int layer = t / 9216, r = t % 9216;
    int k = r / 32, co = r % 32;
    int set = layer >> 2, s = layer & 3;
    const float* src = set == 0 ? pw1 : set == 1 ? pw2 : set == 2 ? rw1 : rw2;
    wt[t] = src[s * 9216 + co * 288 + k];
  } else if (t < 147456 + NV) {
    int v = t - 147456;
    const float* e = emb + v * 32;
    float r[8];
#pragma unroll
    for (int j = 0; j < 8; j++) r[j] = __fmul_rn(e[j], e[j]);
#pragma unroll
    for (int i = 8; i < 32; i += 8)
#pragma unroll
      for (int j = 0; j < 8; j++) r[j] = __fadd_rn(r[j], __fmul_rn(e[i + j], e[i + j]));
    ee[v] = __fadd_rn(__fadd_rn(__fadd_rn(r[0], r[1]), __fadd_rn(r[2], r[3])),
                      __fadd_rn(__fadd_rn(r[4], r[5]), __fadd_rn(r[6], r[7])));
  } else if (t < 147456 + NV + 65536) {
    int idx = t - 147456 - NV;
    float x = emb[idx], hb;
    eh[idx] = bf_split(x, hb);
    float lb;
    el[idx] = bf_split(__fsub_rn(x, hb), lb);
  }
}

// ---------------------------------------------------------------------------
// conv3x3: one thread = one pixel, ALL 32 co. 768 x 192 = 3 blocks/CU.
// Tap double-buffer; s_load weights. Chains (ci,dy,dx) ascending — bit-exact.
// MODE 0: patch-major in -> patch-major out
// MODE 1: residual in (x - acc, image layout) -> patch-major out
// MODE 2: patch-major in; fold: acc_img += zq*0.5 + (conv+b)*0.5
// MODE 3: scale-0 residual (x only, no acc read) -> patch-major out
// MODE 4: scale-0 fold: acc_img = 0 + (zq*0.5 + (conv+b)*0.5) (no acc read)
// ---------------------------------------------------------------------------
template <int MODE>
__global__ __launch_bounds__(192, 3) void conv32_kernel(
    const float* __restrict__ in, const float* __restrict__ x,
    const float* __restrict__ accin, float* __restrict__ outb,
    const float* __restrict__ zqb, float* __restrict__ acc,
    const float* __restrict__ wt, const float* __restrict__ bias, int p, int nw) {
  int t = blockIdx.x * 192 + threadIdx.x;
  int pp = p * p;
  int px = t % p; int t1 = t / p;
  int py = t1 % p;
  int n  = t1 / p;
  int i = n / nw, j = n % nw;

  const bool IMGIN = (MODE == 1 || MODE == 3);
  int off[9]; bool msk[9];
#pragma unroll
  for (int dy = 0; dy < 3; dy++) {
    int ly = py + dy - 1;
    bool vy = (unsigned)ly < (unsigned)p;
    int cy = vy ? ly : 0;
#pragma unroll
    for (int dx = 0; dx < 3; dx++) {
      int lx = px + dx - 1;
      bool vx = (unsigned)lx < (unsigned)p;
      int cx = vx ? lx : 0;
      msk[dy * 3 + dx] = vy && vx;
      if (IMGIN) off[dy * 3 + dx] = (i * p + cy) * WIDTH + (j * p + cx);
      else       off[dy * 3 + dx] = cy * p + cx;
    }
  }

  const float* pin = IMGIN ? nullptr : in + (size_t)n * NCH * pp;

  float a[NCH];
#pragma unroll
  for (int co = 0; co < NCH; co++) a[co] = 0.0f;

  float tv[9], tn[9];
#pragma unroll
  for (int k = 0; k < 9; k++) {
    float v;
    if (MODE == 1)      v = __fsub_rn(x[(size_t)off[k]], accin[(size_t)off[k]]);
    else if (MODE == 3) v = x[(size_t)off[k]];
    else                v = pin[off[k]];
    tv[k] = msk[k] ? v : 0.0f;
  }

  for (int ci = 0; ci < NCH; ci++) {
    if (ci + 1 < NCH) {
#pragma unroll
      for (int k = 0; k < 9; k++) {
        float v;
        if (MODE == 1) {
          size_t ad = (size_t)(ci + 1) * HW + off[k];
          v = __fsub_rn(x[ad], accin[ad]);
        } else if (MODE == 3) {
          v = x[(size_t)(ci + 1) * HW + off[k]];
        } else {
          v = pin[(size_t)(ci + 1) * pp + off[k]];
        }
        tn[k] = msk[k] ? v : 0.0f;
      }
    }
    const float* wp = wt + ci * 288;        // [k][co], uniform -> s_load
#pragma unroll
    for (int k = 0; k < 9; k++) {
#pragma unroll
      for (int co = 0; co < NCH; co++)
        a[co] = fmaf(tv[k], wp[k * 32 + co], a[co]);
    }
#pragma unroll
    for (int k = 0; k < 9; k++) tv[k] = tn[k];
  }

#pragma unroll
  for (int co = 0; co < NCH; co++) {
    float r = __fadd_rn(a[co], bias[co]);
    if (MODE == 2 || MODE == 4) {
      size_t img = (size_t)co * HW + (size_t)(i * p + py) * WIDTH + (j * p + px);
      size_t pt  = (size_t)n * NCH * pp + (size_t)co * pp + (size_t)py * p + px;
      float dec = __fadd_rn(__fmul_rn(zqb[pt], 0.5f), __fmul_rn(r, 0.5f));
      if (MODE == 2) acc[img] = __fadd_rn(acc[img], dec);
      else           acc[img] = __fadd_rn(0.0f, dec);   // 0+dec, same as ref
    } else {
      outb[(size_t)n * NCH * pp + (size_t)co * pp + (size_t)py * p + px] = r;
    }
  }
}

// ---------------------------------------------------------------------------
// GroupNorm stats v2: C lanes per group, shfl_xor butterfly (bit-exact).
// ---------------------------------------------------------------------------
__global__ __launch_bounds__(64) void gn_stats_kernel(
    const float* __restrict__ buf, float2* __restrict__ stats,
    int p, int C, int chunk) {
  int tid = threadIdx.x;
  int gpw = 64 / C;
  int gi = tid / C, cl = tid % C;
  int grp = blockIdx.x * gpw + gi;
  int pp = p * p, ne = 4 * pp;
  const float* base = buf + ((size_t)(grp >> 3) * NCH + (size_t)(grp & 7) * 4) * pp
                      + (size_t)cl * chunk;

  float s = np_pw<0>(base, chunk, 0.0f);
  for (int m = 1; m < C; m <<= 1) s = __fadd_rn(s, __shfl_xor(s, m, 64));
  float mu = __fdiv_rn(s, (float)ne);

  float s2 = np_pw<1>(base, chunk, mu);
  for (int m = 1; m < C; m <<= 1) s2 = __fadd_rn(s2, __shfl_xor(s2, m, 64));

  if (cl == 0) {
    float var = __fdiv_rn(s2, (float)ne);
    float rs = __fdiv_rn(1.0f, __fsqrt_rn(__fadd_rn(var, 1e-5f)));
    stats[grp] = make_float2(mu, rs);
  }
}

// ---------------------------------------------------------------------------
// GN affine + exact GELU (erf = f64 erf rounded to f32).
// ---------------------------------------------------------------------------
__global__ __launch_bounds__(256) void gn_gelu_kernel(
    float* __restrict__ buf, const float2* __restrict__ stats,
    const float* __restrict__ gamma, const float* __restrict__ beta, int p) {
  int t = blockIdx.x * 256 + threadIdx.x;
  int pp = p * p;
  int t2 = t / pp;
  int c = t2 % NCH;
  int n = t2 / NCH;
  float2 st = stats[n * 8 + (c >> 2)];
  float v = __fadd_rn(__fmul_rn(__fmul_rn(__fsub_rn(buf[t], st.x), st.y), gamma[c]), beta[c]);
  float tt = __fdiv_rn(v, 1.41421356237309504880f);
  float e = (float)erf((double)tt);
  buf[t] = __fmul_rn(__fmul_rn(0.5f, v), __fadd_rn(1.0f, e));
}

// ---------------------------------------------------------------------------
// MFMA filter pass with fused zsplit (round-18/19 known-good).
// ---------------------------------------------------------------------------
__global__ __launch_bounds__(576, 5) void gemm_min_kernel(
    const float* __restrict__ z,
    const unsigned short* __restrict__ EH, const unsigned short* __restrict__ EL,
    const float* __restrict__ EE,
    float* __restrict__ BD, float* __restrict__ B2, int* __restrict__ I1) {
  __shared__ float ee_l[2048];
  int tid = threadIdx.x;
  for (int i = tid; i < 2048; i += 576) ee_l[i] = EE[i];
  __syncthreads();

  int wid = tid / 64, lane = tid & 63;
  int t0 = blockIdx.x * 18 + wid * 2;        // two consecutive row-tiles
  int lr = lane & 15, lg = lane >> 4;

  float za0[8], za1[8];
  {
    const float4* zp0 = (const float4*)(z + (size_t)(t0 * 16 + lr) * 32 + 8 * lg);
    const float4* zp1 = (const float4*)(z + (size_t)((t0 + 1) * 16 + lr) * 32 + 8 * lg);
    float4 c0 = zp0[0], c1 = zp0[1], d0 = zp1[0], d1 = zp1[1];
    za0[0]=c0.x; za0[1]=c0.y; za0[2]=c0.z; za0[3]=c0.w;
    za0[4]=c1.x; za0[5]=c1.y; za0[6]=c1.z; za0[7]=c1.w;
    za1[0]=d0.x; za1[1]=d0.y; za1[2]=d0.z; za1[3]=d0.w;
    za1[4]=d1.x; za1[5]=d1.y; za1[6]=d1.z; za1[7]=d1.w;
  }

  // exact numpy zz via cross-lane reconstruction (chain order preserved)
  float zz0, zz1;
  {
    float r0[8], r1[8];
#pragma unroll
    for (int j = 0; j < 8; j++) {
      float p0 = __fmul_rn(za0[j], za0[j]);
      float p1 = __fmul_rn(za1[j], za1[j]);
      float a0 = __shfl(p0, lr, 64),      a1 = __shfl(p0, 16 + lr, 64);
      float a2 = __shfl(p0, 32 + lr, 64), a3 = __shfl(p0, 48 + lr, 64);
      r0[j] = __fadd_rn(__fadd_rn(__fadd_rn(a0, a1), a2), a3);
      float b0 = __shfl(p1, lr, 64),      b1 = __shfl(p1, 16 + lr, 64);
      float b2_ = __shfl(p1, 32 + lr, 64), b3 = __shfl(p1, 48 + lr, 64);
      r1[j] = __fadd_rn(__fadd_rn(__fadd_rn(b0, b1), b2_), b3);
    }
    zz0 = __fadd_rn(__fadd_rn(__fadd_rn(r0[0], r0[1]), __fadd_rn(r0[2], r0[3])),
                    __fadd_rn(__fadd_rn(r0[4], r0[5]), __fadd_rn(r0[6], r0[7])));
    zz1 = __fadd_rn(__fadd_rn(__fadd_rn(r1[0], r1[1]), __fadd_rn(r1[2], r1[3])),
                    __fadd_rn(__fadd_rn(r1[4], r1[5]), __fadd_rn(r1[6], r1[7])));
  }
  float zzv[8];
#pragma unroll
  for (int r = 0; r < 4; r++) {
    zzv[r]     = __shfl(zz0, 4 * lg + r, 64);
    zzv[4 + r] = __shfl(zz1, 4 * lg + r, 64);
  }

  vshort8 azh0, azl0, azh1, azl1;
#pragma unroll
  for (int j = 0; j < 8; j++) {
    float hb;
    azh0[j] = (short)bf_split(za0[j], hb);
    float lb;
    azl0[j] = (short)bf_split(__fsub_rn(za0[j], hb), lb);
    azh1[j] = (short)bf_split(za1[j], hb);
    azl1[j] = (short)bf_split(__fsub_rn(za1[j], hb), lb);
  }

  float b1[8], b2[8]; int i1[8];
#pragma unroll
  for (int r = 0; r < 8; r++) { b1[r] = 3.402823466e+38f; b2[r] = 3.402823466e+38f; i1[r] = 0; }

  vshort8 nbeh = *(const vshort8*)(EH + (size_t)lr * 32 + 8 * lg);
  vshort8 nbel = *(const vshort8*)(EL + (size_t)lr * 32 + 8 * lg);

  for (int ct = 0; ct < 128; ct++) {
    vshort8 beh = nbeh, bel = nbel;
    if (ct + 1 < 128) {
      nbeh = *(const vshort8*)(EH + (size_t)((ct + 1) * 16 + lr) * 32 + 8 * lg);
      nbel = *(const vshort8*)(EL + (size_t)((ct + 1) * 16 + lr) * 32 + 8 * lg);
    }
    vfloat4 acc0 = {0.0f, 0.0f, 0.0f, 0.0f};
    acc0 = __builtin_amdgcn_mfma_f32_16x16x32_bf16(azh0, beh, acc0, 0, 0, 0);
    acc0 = __builtin_amdgcn_mfma_f32_16x16x32_bf16(azh0, bel, acc0, 0, 0, 0);
    acc0 = __builtin_amdgcn_mfma_f32_16x16x32_bf16(azl0, beh, acc0, 0, 0, 0);
    vfloat4 acc1 = {0.0f, 0.0f, 0.0f, 0.0f};
    acc1 = __builtin_amdgcn_mfma_f32_16x16x32_bf16(azh1, beh, acc1, 0, 0, 0);
    acc1 = __builtin_amdgcn_mfma_f32_16x16x32_bf16(azh1, bel, acc1, 0, 0, 0);
    acc1 = __builtin_amdgcn_mfma_f32_16x16x32_bf16(azl1, beh, acc1, 0, 0, 0);
    int col = ct * 16 + lr;
    float eev = ee_l[col];
#pragma unroll
    for (int r = 0; r < 4; r++) {
      float d = (zzv[r] + eev) - 2.0f * acc0[r];
      if (d < b1[r]) { b2[r] = b1[r]; b1[r] = d; i1[r] = col; }
      else b2[r] = fminf(b2[r], d);
      float d1 = (zzv[4 + r] + eev) - 2.0f * acc1[r];
      if (d1 < b1[4 + r]) { b2[4 + r] = b1[4 + r]; b1[4 + r] = d1; i1[4 + r] = col; }
      else b2[4 + r] = fminf(b2[4 + r], d1);
    }
  }

  for (int m = 1; m < 16; m <<= 1) {
#pragma unroll
    for (int r = 0; r < 8; r++) {
      float ob1 = __shfl_xor(b1[r], m, 64);
      int   oi1 = __shfl_xor(i1[r], m, 64);
      float ob2 = __shfl_xor(b2[r], m, 64);
      bool aw = (b1[r] < ob1) || (b1[r] == ob1 && i1[r] < oi1);
      float lo = aw ? ob1 : b1[r];
      b1[r] = aw ? b1[r] : ob1;
      i1[r] = aw ? i1[r] : oi1;
      b2[r] = fminf(fminf(b2[r], ob2), lo);
    }
  }

  if (lr == 0) {
#pragma unroll
    for (int r = 0; r < 4; r++) {
      int row0 = t0 * 16 + 4 * lg + r;
      BD[row0] = b1[r]; B2[row0] = b2[r]; I1[row0] = i1[r];
      int row1 = (t0 + 1) * 16 + 4 * lg + r;
      BD[row1] = b1[4 + r]; B2[row1] = b2[4 + r]; I1[row1] = i1[4 + r];
    }
  }
}

// ---------------------------------------------------------------------------
// Epilogue pass A (r17/r19 known-good): 4 threads/row, float4; preliminary
// zq/idx for all rows, per-quarter f64 SSE, flagged-row compaction.
// ---------------------------------------------------------------------------
__global__ __launch_bounds__(256) void epilogue_kernel(
    const float* __restrict__ z, const float* __restrict__ emb,
    const float* __restrict__ BD, const float* __restrict__ B2,
    const int* __restrict__ I1, float* __restrict__ zq,
    float* __restrict__ idxout, double* __restrict__ ssep,
    int* __restrict__ list, int* __restrict__ cnt) {
  int t = blockIdx.x * 256 + threadIdx.x;   // grid exact: 2304*256 = 589824
  int row = t >> 2, part = t & 3;
  float bd = BD[row];
  int bi = I1[row];
  float margin = __fadd_rn(1.0e-6f, __fmul_rn(5.0e-7f, fabsf(bd)));
  bool flagged = (B2[row] - bd) <= margin;
  if (flagged && part == 0) {
    int i = atomicAdd(cnt, 1);
    list[i] = row;
  }
  const float4* ep = (const float4*)(emb + (size_t)bi * 32 + part * 8);
  const float4* zp = (const float4*)(z + (size_t)row * 32 + part * 8);
  float4* qp = (float4*)(zq + (size_t)row * 32 + part * 8);
  float4 e0 = ep[0], e1 = ep[1];
  float4 z0 = zp[0], z1 = zp[1];
  qp[0] = e0; qp[1] = e1;
  double sse = 0.0, d;
  d = (double)e0.x - (double)z0.x; sse += d * d;
  d = (double)e0.y - (double)z0.y; sse += d * d;
  d = (double)e0.z - (double)z0.z; sse += d * d;
  d = (double)e0.w - (double)z0.w; sse += d * d;
  d = (double)e1.x - (double)z1.x; sse += d * d;
  d = (double)e1.y - (double)z1.y; sse += d * d;
  d = (double)e1.z - (double)z1.z; sse += d * d;
  d = (double)e1.w - (double)z1.w; sse += d * d;
  ssep[t] = sse;
  if (part == 0) idxout[row] = (float)bi;
}

// ---------------------------------------------------------------------------
// Pass B: wave-per-flagged-row exact rescore (grid-stride over LIST).
// Identical f32 chains + lex-(d,v) butterfly = np.argmin first-occurrence.
// ---------------------------------------------------------------------------
__global__ __launch_bounds__(64) void rescore_kernel(
    const float* __restrict__ z, const float* __restrict__ emb,
    const float* __restrict__ EE,
    float* __restrict__ zq, float* __restrict__ idxout,
    double* __restrict__ ssep, const int* __restrict__ list,
    const int* __restrict__ cnt) {
  int lane = threadIdx.x;
  int n = *cnt;
  for (int i = blockIdx.x; i < n; i += gridDim.x) {
    int row = list[i];
    const float* zp = z + (size_t)row * 32;  // wave-uniform -> scalar loads
    float zb[32];
#pragma unroll
    for (int q = 0; q < 32; q++) zb[q] = zp[q];
    // exact numpy zz chain
    float rr[8];
#pragma unroll
    for (int j = 0; j < 8; j++) rr[j] = __fmul_rn(zb[j], zb[j]);
#pragma unroll
    for (int ii = 8; ii < 32; ii += 8)
#pragma unroll
      for (int j = 0; j < 8; j++) rr[j] = __fadd_rn(rr[j], __fmul_rn(zb[ii + j], zb[ii + j]));
    float zzb = __fadd_rn(__fadd_rn(__fadd_rn(rr[0], rr[1]), __fadd_rn(rr[2], rr[3])),
                          __fadd_rn(__fadd_rn(rr[4], rr[5]), __fadd_rn(rr[6], rr[7])));
    float bestd = 3.402823466e+38f;
    int bestv = NV;
    for (int k = 0; k < 32; k++) {
      int v = lane + 64 * k;
      const float* e0 = emb + (size_t)v * 32;
      float m = 0.0f;
#pragma unroll
      for (int q = 0; q < 32; q++) m = fmaf(zb[q], e0[q], m);
      float d = __fsub_rn(__fadd_rn(zzb, EE[v]), __fmul_rn(2.0f, m));
      if (d < bestd) { bestd = d; bestv = v; } // v ascending within lane
    }
    for (int mm = 1; mm < 64; mm <<= 1) {      // lexicographic (d, v) butterfly
      float od = __shfl_xor(bestd, mm, 64);
      int ov = __shfl_xor(bestv, mm, 64);
      if (od < bestd || (od == bestd && ov < bestv)) { bestd = od; bestv = ov; }
    }
    if (lane < 32) zq[(size_t)row * 32 + lane] = emb[bestv * 32 + lane];
    if (lane < 4) {
      const float* ep = emb + bestv * 32 + lane * 8;
      const float* zr = z + (size_t)row * 32 + lane * 8;
      double sse = 0.0;
#pragma unroll
      for (int q = 0; q < 8; q++) {
        double dd = (double)ep[q] - (double)zr[q];
        sse += dd * dd;
      }
      ssep[row * 4 + lane] = sse;
    }
    if (lane == 0) idxout[row] = (float)bestv;
  }
}

// ---------------------------------------------------------------------------
// Pass C: deterministic fixed-order reduction of ssep -> PART.
// ---------------------------------------------------------------------------
__global__ __launch_bounds__(256) void ssered_kernel(
    const double* __restrict__ ssep, double* __restrict__ part) {
  __shared__ double red[256];
  int t = blockIdx.x * 256 + threadIdx.x;   // grid exact: 576*256
  const double* b = ssep + (size_t)t * 4;
  red[threadIdx.x] = ((b[0] + b[1]) + (b[2] + b[3]));
  __syncthreads();
  for (int st = 128; st > 0; st >>= 1) {
    if (threadIdx.x < st) red[threadIdx.x] += red[threadIdx.x + st];
    __syncthreads();
  }
  if (threadIdx.x == 0) part[blockIdx.x] = red[0];
}

__global__ __launch_bounds__(256) void sigmoid_kernel(
    const float* __restrict__ acc, float* __restrict__ out) {
  int t = blockIdx.x * 256 + threadIdx.x;
  out[t] = (float)(1.0 / (1.0 + exp(-(double)acc[t])));
}

// 256-thread deterministic loss reduction over 4 x 576 partials
__global__ __launch_bounds__(256) void loss_kernel(
    const double* __restrict__ part, float* __restrict__ out) {
  __shared__ double red[256];
  int tid = threadIdx.x;
  double tot = 0.0;
  for (int s = 0; s < 4; s++) {
    double sse = 0.0;
    for (int b = tid; b < 576; b += 256) sse += part[s * 1024 + b];
    red[tid] = sse;
    __syncthreads();
    for (int st = 128; st > 0; st >>= 1) {
      if (tid < st) red[tid] += red[tid + st];
      __syncthreads();
    }
    if (tid == 0) tot += 1.25 * red[0] / 4718592.0;
    __syncthreads();
  }
  if (tid == 0) out[0] = (float)tot;
}

// ---------------------------------------------------------------------------
extern "C" void kernel_launch(void* const* d_in, const int* in_sizes, int n_in,
                              void* d_out, int out_size, void* d_ws, size_t ws_size,
                              hipStream_t stream) {
  const float* X   = (const float*)d_in[0];
  const float* EMB = (const float*)d_in[1];
  const float* PW1 = (const float*)d_in[2];
  const float* PB1 = (const float*)d_in[3];
  const float* PG  = (const float*)d_in[4];
  const float* PBT = (const float*)d_in[5];
  const float* PW2 = (const float*)d_in[6];
  const float* PB2 = (const float*)d_in[7];
  const float* RW1 = (const float*)d_in[8];
  const float* RB1 = (const float*)d_in[9];
  const float* RG  = (const float*)d_in[10];
  const float* RBT = (const float*)d_in[11];
  const float* RW2 = (const float*)d_in[12];
  const float* RB2 = (const float*)d_in[13];
  float* out = (float*)d_out;

  // workspace layout (~65 MiB; ws >= 115 MB established safe):
  char* w = (char*)d_ws;
  float*          EE    = (float*)(w);                      // 8,192
  float*          WT    = (float*)(w + 8192UL);             // 589,824
  unsigned short* EH    = (unsigned short*)(w + 598016UL);  // 131,072
  unsigned short* EL    = (unsigned short*)(w + 729088UL);  // 131,072
  float2*         STATS = (float2*)(w + 860160UL);          // 36,864
  double*         PART  = (double*)(w + 897024UL);          // 32,768
  float*          BD    = (float*)(w + 929792UL);           // 589,824
  float*          B2    = (float*)(w + 1519616UL);          // 589,824
  int*            I1    = (int*)(w + 2109440UL);            // 589,824
  float*          P     = (float*)(w + 2699264UL);          // 18,874,368
  float*          H     = (float*)(w + 21573632UL);         // 18,874,368
  float*          ACC   = (float*)(w + 40448000UL);         // 18,874,368
  int*            CNT   = (int*)(w + 59322368UL);           // 64
  int*            LIST  = (int*)(w + 59322432UL);           // 589,824
  double*         SSEP  = (double*)(w + 59912256UL);        // 4,718,592

  hipMemsetAsync(CNT, 0, 64UL, stream);
  prep_kernel<<<840, 256, 0, stream>>>(PW1, PW2, RW1, RW2, EMB, WT, EE, EH, EL);

  const int PS[4] = {16, 32, 48, 64};
  for (int s = 0; s < 4; s++) {
    int p = PS[s], nw = 384 / p, N = nw * nw;
    int C = (p == 16) ? 8 : (p == 32) ? 32 : 64;      // numpy-split-aligned chunks
    int chunk = (4 * p * p) / C;
    int gblocks = (N * 8 * C) / 64;
    const float* wt_p1 = WT + (0 * 4 + s) * 9216;
    const float* wt_p2 = WT + (1 * 4 + s) * 9216;
    const float* wt_r1 = WT + (2 * 4 + s) * 9216;
    const float* wt_r2 = WT + (3 * 4 + s) * 9216;

    // conv_block #1 (fused unfold): (x - acc) -> H, GN+GELU in H, H -> P (z)
    if (s == 0)
      conv32_kernel<3><<<768, 192, 0, stream>>>(nullptr, X, nullptr, H, nullptr, nullptr,
                                                wt_p1, PB1 + s * 32, p, nw);
    else
      conv32_kernel<1><<<768, 192, 0, stream>>>(nullptr, X, ACC, H, nullptr, nullptr,
                                                wt_p1, PB1 + s * 32, p, nw);
    gn_stats_kernel<<<gblocks, 64, 0, stream>>>(H, STATS, p, C, chunk);
    gn_gelu_kernel<<<18432, 256, 0, stream>>>(H, STATS, PG + s * 32, PBT + s * 32, p);
    conv32_kernel<0><<<768, 192, 0, stream>>>(H, nullptr, nullptr, P, nullptr, nullptr,
                                              wt_p2, PB2 + s * 32, p, nw);
    // quantize: fused zsplit+filter GEMM + BW epilogue + rescore + reduce
    gemm_min_kernel<<<512, 576, 0, stream>>>(P, EH, EL, EE, BD, B2, I1);
    epilogue_kernel<<<2304, 256, 0, stream>>>(P, EMB, BD, B2, I1, H,
                                              out + 4718592 + s * 147456, SSEP,
                                              LIST, CNT + s);
    rescore_kernel<<<1024, 64, 0, stream>>>(P, EMB, EE, H,
                                            out + 4718592 + s * 147456, SSEP,
                                            LIST, CNT + s);
    ssered_kernel<<<576, 256, 0, stream>>>(SSEP, PART + s * 1024);
    // residual conv_block on zq: H -> P, GN+GELU in P, conv+fold into ACC
    conv32_kernel<0><<<768, 192, 0, stream>>>(H, nullptr, nullptr, P, nullptr, nullptr,
                                              wt_r1, RB1 + s * 32, p, nw);
    gn_stats_kernel<<<gblocks, 64, 0, stream>>>(P, STATS, p, C, chunk);
    gn_gelu_kernel<<<18432, 256, 0, stream>>>(P, STATS, RG + s * 32, RBT + s * 32, p);
    if (s == 0)
      conv32_kernel<4><<<768, 192, 0, stream>>>(P, nullptr, nullptr, nullptr, H, ACC,
                                                wt_r2, RB2 + s * 32, p, nw);
    else
      conv32_kernel<2><<<768, 192, 0, stream>>>(P, nullptr, nullptr, nullptr, H, ACC,
                                                wt_r2, RB2 + s * 32, p, nw);
  }

  sigmoid_kernel<<<18432, 256, 0, stream>>>(ACC, out);
  loss_kernel<<<1, 256, 0, stream>>>(PART, out + 5308416);
}